// Round 16
// baseline (291.088 us; speedup 1.0000x reference)
//
#include <hip/hip_runtime.h>
#include <hip/hip_bf16.h>

typedef __attribute__((ext_vector_type(8))) short bf16x8;
typedef __attribute__((ext_vector_type(4))) float f32x4;
typedef __attribute__((ext_vector_type(4))) unsigned short u16x4;

#define MFMA16(a, b, c) __builtin_amdgcn_mfma_f32_16x16x32_bf16(a, b, c, 0, 0, 0)

#define SCALE 0.21022410381342865f /* 512^(-1/4) */

__device__ __forceinline__ unsigned short f2bf(float f) {
    union { float f; unsigned u; } v; v.f = f;
    unsigned r = v.u + 0x7FFF + ((v.u >> 16) & 1);
    return (unsigned short)(r >> 16);
}

__device__ __forceinline__ unsigned cvtpk(float lo, float hi) {
    unsigned r;
    asm("v_cvt_pk_bf16_f32 %0, %1, %2" : "=v"(r) : "v"(lo), "v"(hi));
    return r;
}

typedef __attribute__((address_space(3))) void lds_void;
typedef const __attribute__((address_space(1))) void gbl_void;
__device__ __forceinline__ void g2l16(const void* g, void* l) {
    __builtin_amdgcn_global_load_lds((gbl_void*)g, (lds_void*)l, 16, 0, 0);
}

#define PHASE_BARRIER() do { \
    asm volatile("s_waitcnt vmcnt(0) lgkmcnt(0)" ::: "memory"); \
    __builtin_amdgcn_s_barrier(); \
    __builtin_amdgcn_sched_barrier(0); \
} while (0)

#define LGKM_BARRIER() do { \
    asm volatile("s_waitcnt lgkmcnt(0)" ::: "memory"); \
    __builtin_amdgcn_s_barrier(); \
    __builtin_amdgcn_sched_barrier(0); \
} while (0)

// --------------------------------------- prep: gn_stats + weight cast/T
// grid 5120: blocks 0..4095 = wprep work, 4096..5119 = gn stats partials.
__global__ __launch_bounds__(256) void prep_kernel(
    const float* __restrict__ x,
    const float* __restrict__ Wq, const float* __restrict__ Wk,
    const float* __restrict__ Wv, const float* __restrict__ Wp,
    float2* __restrict__ gstats,
    unsigned short* __restrict__ wqkvt, unsigned short* __restrict__ wpt)
{
    __shared__ float rs_[4], rss_[4];
    if (blockIdx.x < 4096) {
        int idx = blockIdx.x * 256 + threadIdx.x; // 1,048,576 total
        if (idx < 786432) {
            int n = idx >> 9, k = idx & 511;
            int j = n >> 9, nn = n & 511;
            const float* W = (j == 0) ? Wq : (j == 1) ? Wk : Wv;
            wqkvt[idx] = f2bf(W[k * 512 + nn]);
        } else {
            int i2 = idx - 786432;
            int n = i2 >> 9, k = i2 & 511;
            wpt[i2] = f2bf(Wp[k * 512 + n]);
        }
        return;
    }
    int id = blockIdx.x - 4096;
    int b = id >> 8, rem = id & 255;
    int g = rem >> 3, sl = rem & 7;
    int t = threadIdx.x;
    const float4* xf4 = (const float4*)x;
    size_t base4 = (size_t)b * (4096 * 128) + g * 4;

    float s = 0.f, ss = 0.f;
#pragma unroll
    for (int i = 0; i < 8; ++i) {
        int flat = i * 256 + t;
        int hw = sl * 512 + (flat >> 2), c4 = flat & 3;
        float4 v = xf4[base4 + (size_t)hw * 128 + c4];
        s  += v.x + v.y + v.z + v.w;
        ss += v.x * v.x + v.y * v.y + v.z * v.z + v.w * v.w;
    }
    for (int m = 32; m >= 1; m >>= 1) { s += __shfl_xor(s, m); ss += __shfl_xor(ss, m); }
    int wv = t >> 6;
    if ((t & 63) == 0) { rs_[wv] = s; rss_[wv] = ss; }
    __syncthreads();
    if (t == 0) {
        float2 o;
        o.x = rs_[0] + rs_[1] + rs_[2] + rs_[3];
        o.y = rss_[0] + rss_[1] + rss_[2] + rss_[3];
        gstats[id] = o;
    }
}

// ------------------------------------------------------- GroupNorm apply
__global__ __launch_bounds__(256) void gn_apply(
    const float* __restrict__ x, const float* __restrict__ gamma,
    const float* __restrict__ beta, const float2* __restrict__ gstats,
    unsigned short* __restrict__ xn)
{
    int id = blockIdx.x;
    int b = id >> 9, rem = id & 511;
    int g = rem >> 4, sl = rem & 15;
    int t = threadIdx.x;

    float s = 0.f, ss = 0.f;
#pragma unroll
    for (int i = 0; i < 8; ++i) {
        float2 p = gstats[(b * 32 + g) * 8 + i];
        s += p.x; ss += p.y;
    }
    float mean = s * (1.f / 65536.f);
    float var  = ss * (1.f / 65536.f) - mean * mean;
    float rstd = rsqrtf(var + 1e-6f);

    const float4* xf4 = (const float4*)x;
    const float4* g4 = (const float4*)gamma;
    const float4* b4 = (const float4*)beta;
    size_t base4 = (size_t)b * (4096 * 128) + g * 4;
#pragma unroll
    for (int i = 0; i < 4; ++i) {
        int flat = i * 256 + t;
        int hw = sl * 256 + (flat >> 2), c4 = flat & 3;
        float4 v  = xf4[base4 + (size_t)hw * 128 + c4];
        float4 gm = g4[g * 4 + c4], bt = b4[g * 4 + c4];
        u16x4 o;
        o.x = f2bf((v.x - mean) * rstd * gm.x + bt.x);
        o.y = f2bf((v.y - mean) * rstd * gm.y + bt.y);
        o.z = f2bf((v.z - mean) * rstd * gm.z + bt.z);
        o.w = f2bf((v.w - mean) * rstd * gm.w + bt.w);
        *(u16x4*)&xn[(size_t)(b * 4096 + hw) * 512 + g * 16 + c4 * 4] = o;
    }
}

// ------------------------------------------------------------- bf16 GEMM v2
template <int MODE>
__global__ __launch_bounds__(256, 4) void gemm_kernel(
    const unsigned short* __restrict__ A, const unsigned short* __restrict__ Bt,
    const float* __restrict__ bias_q, const float* __restrict__ bias_k,
    const float* __restrict__ bias_v, const float* __restrict__ bias_p,
    const float* __restrict__ resid,
    unsigned short* __restrict__ Cbf, float* __restrict__ Cf)
{
    int m0 = blockIdx.x * 128;
    int n0 = blockIdx.y * 128;
    int t = threadIdx.x;
    int l = t & 63, w = t >> 6;
    int wm = w >> 1, wn = w & 1;
    int lr = l & 15, lg = l >> 4;

    __shared__ __align__(16) unsigned short lds[16384];  // 32 KB
    unsigned short* As = lds;
    unsigned short* Bs = lds + 8192;

    const unsigned short* A_ = A + (size_t)m0 * 512;
    const unsigned short* B_ = Bt + (size_t)n0 * 512;

    auto stage = [&](int s) {
        int k0 = s * 64;
#pragma unroll
        for (int c = 0; c < 4; ++c) {
            int flat = c * 256 + t;
            int row = flat >> 3, u = flat & 7;
            g2l16(A_ + (size_t)row * 512 + k0 + ((u ^ (row & 7)) << 3),
                  As + (flat << 3));
        }
#pragma unroll
        for (int c = 0; c < 4; ++c) {
            int flat = c * 256 + t;
            int row = flat >> 3, u = flat & 7;
            g2l16(B_ + (size_t)row * 512 + k0 + ((u ^ (row & 7)) << 3),
                  Bs + (flat << 3));
        }
    };

    f32x4 acc[4][4];
#pragma unroll
    for (int i = 0; i < 4; ++i)
#pragma unroll
        for (int j = 0; j < 4; ++j) acc[i][j] = f32x4{0.f, 0.f, 0.f, 0.f};

    for (int s = 0; s < 8; ++s) {
        if (s) LGKM_BARRIER();
        stage(s);
        PHASE_BARRIER();
        __builtin_amdgcn_s_setprio(1);
#pragma unroll
        for (int ks = 0; ks < 2; ++ks) {
            bf16x8 af[4], bfr[4];
#pragma unroll
            for (int mi = 0; mi < 4; ++mi) {
                int row = wm * 64 + mi * 16 + lr;
                af[mi] = *(const bf16x8*)&As[(row * 8 + ((ks * 4 + lg) ^ (row & 7))) << 3];
            }
#pragma unroll
            for (int ni = 0; ni < 4; ++ni) {
                int row = wn * 64 + ni * 16 + lr;
                bfr[ni] = *(const bf16x8*)&Bs[(row * 8 + ((ks * 4 + lg) ^ (row & 7))) << 3];
            }
#pragma unroll
            for (int mi = 0; mi < 4; ++mi)
#pragma unroll
                for (int ni = 0; ni < 4; ++ni)
                    acc[mi][ni] = MFMA16(af[mi], bfr[ni], acc[mi][ni]);
        }
        __builtin_amdgcn_s_setprio(0);
    }

#pragma unroll
    for (int mi = 0; mi < 4; ++mi)
#pragma unroll
        for (int ni = 0; ni < 4; ++ni)
#pragma unroll
            for (int r = 0; r < 4; ++r) {
                int row = m0 + wm * 64 + mi * 16 + lg * 4 + r;
                int col = n0 + wn * 64 + ni * 16 + lr;
                float val = acc[mi][ni][r];
                if (MODE == 0) {
                    float bias, scl;
                    if (col < 512)       { bias = bias_q[col];        scl = SCALE; }
                    else if (col < 1024) { bias = bias_k[col - 512];  scl = SCALE; }
                    else                 { bias = bias_v[col - 1024]; scl = 1.0f;  }
                    Cbf[(size_t)row * 1536 + col] = f2bf((val + bias) * scl);
                } else {
                    Cf[(size_t)row * 512 + col] =
                        val + bias_p[col] + resid[(size_t)row * 512 + col];
                }
            }
}

// ------------------------------------------------ V transpose to [b][d][n]
__global__ __launch_bounds__(256) void vtrans(
    const unsigned short* __restrict__ qkv, unsigned short* __restrict__ vT)
{
    int n0 = blockIdx.x * 64, d0 = blockIdx.y * 64, b = blockIdx.z;
    int t = threadIdx.x;
    __shared__ unsigned short tile[64][72];
    for (int c = 0; c < 2; ++c) {
        int flat = c * 256 + t;
        int r = flat >> 3, cc = (flat & 7) * 8;
        *(bf16x8*)&tile[r][cc] =
            *(const bf16x8*)&qkv[(size_t)(b * 4096 + n0 + r) * 1536 + 1024 + d0 + cc];
    }
    __syncthreads();
    for (int c = 0; c < 2; ++c) {
        int flat = c * 256 + t;
        int dr = flat >> 3, nc = (flat & 7) * 8;
        bf16x8 v;
        for (int j = 0; j < 8; ++j) v[j] = (short)tile[nc + j][dr];
        *(bf16x8*)&vT[((size_t)b * 512 + d0 + dr) * 4096 + n0 + nc] = v;
    }
}

// ------------------------------------------------------------ QK^T + exp v4
__global__ __launch_bounds__(256, 4) void qk_kernel(
    const unsigned short* __restrict__ qkv, unsigned short* __restrict__ P,
    float* __restrict__ lpart, int b0)
{
    int W = blockIdx.x;
    int xcd = W & 7, i = W >> 3;
    int bb = xcd >> 2;
    int nb = (xcd & 3) * 8 + (i & 7);   // q-block
    int mb = i >> 3;                    // kv-block
    int m0 = mb * 128, n0 = nb * 128;
    int b = b0 + bb;

    int t = threadIdx.x, l = t & 63, w = t >> 6;
    int wm = w >> 1, wn = w & 1;
    int lr = l & 15, lg = l >> 4;

    __shared__ __align__(16) unsigned short lds[16896];  // 33 KB
    unsigned short* As = lds;             // K tile 128x64 (kv rows)
    unsigned short* Bs = lds + 8192;      // Q tile 128x64 (q rows)
    float* Lw = (float*)(lds + 16384);    // 2 x 128 row-sum halves

    const unsigned short* A_ = qkv + (size_t)(b * 4096 + m0) * 1536 + 512;  // K
    const unsigned short* B_ = qkv + (size_t)(b * 4096 + n0) * 1536;        // Q

    auto stage = [&](int s) {
        int k0 = s * 64;
#pragma unroll
        for (int c = 0; c < 4; ++c) {
            int flat = c * 256 + t;       // 1024 units: 128 rows x 8
            int row = flat >> 3, u = flat & 7;
            g2l16(A_ + (size_t)row * 1536 + k0 + ((u ^ (row & 7)) << 3),
                  As + (flat << 3));
        }
#pragma unroll
        for (int c = 0; c < 4; ++c) {
            int flat = c * 256 + t;
            int row = flat >> 3, u = flat & 7;
            g2l16(B_ + (size_t)row * 1536 + k0 + ((u ^ (row & 7)) << 3),
                  Bs + (flat << 3));
        }
    };

    f32x4 acc[4][4];
#pragma unroll
    for (int mi = 0; mi < 4; ++mi)
#pragma unroll
        for (int ni = 0; ni < 4; ++ni) acc[mi][ni] = f32x4{0.f, 0.f, 0.f, 0.f};

    for (int s = 0; s < 8; ++s) {
        if (s) LGKM_BARRIER();             // all reads of buf retired
        stage(s);
        PHASE_BARRIER();                   // DMA landed
        __builtin_amdgcn_s_setprio(1);
#pragma unroll
        for (int ks = 0; ks < 2; ++ks) {
            bf16x8 af[4], bfr[4];
#pragma unroll
            for (int mi = 0; mi < 4; ++mi) {
                int row = wm * 64 + mi * 16 + lr;
                af[mi] = *(const bf16x8*)&As[(row * 8 + ((ks * 4 + lg) ^ (row & 7))) << 3];
            }
#pragma unroll
            for (int ni = 0; ni < 4; ++ni) {
                int row = wn * 64 + ni * 16 + lr;
                bfr[ni] = *(const bf16x8*)&Bs[(row * 8 + ((ks * 4 + lg) ^ (row & 7))) << 3];
            }
#pragma unroll
            for (int mi = 0; mi < 4; ++mi)
#pragma unroll
                for (int ni = 0; ni < 4; ++ni)
                    acc[mi][ni] = MFMA16(af[mi], bfr[ni], acc[mi][ni]);
        }
        __builtin_amdgcn_s_setprio(0);
    }
    LGKM_BARRIER();   // last compute's LDS reads retired -> buffers reusable

    // ---- epilogue: exp + in-lane row sums + packed P writes (S^T layout)
    unsigned short* Pl = lds;             // 128 q x 128 kv = 32 KB overlay
    {
        float sums[4] = {0.f, 0.f, 0.f, 0.f};
#pragma unroll
        for (int mi = 0; mi < 4; ++mi) {
            int u = wm * 8 + mi * 2 + (lg >> 1);   // 16B unit (16/row)
            int half = lg & 1;
#pragma unroll
            for (int ni = 0; ni < 4; ++ni) {
                float p0 = __expf(acc[mi][ni][0]);
                float p1 = __expf(acc[mi][ni][1]);
                float p2 = __expf(acc[mi][ni][2]);
                float p3 = __expf(acc[mi][ni][3]);
                sums[ni] += p0 + p1 + p2 + p3;
                int q = wn * 64 + ni * 16 + lr;
                unsigned* dst = (unsigned*)&((char*)Pl)[
                    q * 256 + ((u ^ (q & 7)) << 4) + (half << 3)];
                dst[0] = cvtpk(p0, p1);
                dst[1] = cvtpk(p2, p3);
            }
        }
#pragma unroll
        for (int ni = 0; ni < 4; ++ni) {
            float v = sums[ni];
            v += __shfl_xor(v, 16);
            v += __shfl_xor(v, 32);
            if (lg == 0) Lw[wm * 128 + wn * 64 + ni * 16 + lr] = v;
        }
    }
    LGKM_BARRIER();

    if (t < 128)
        lpart[(size_t)(bb * 32 + mb) * 4096 + n0 + t] = Lw[t] + Lw[128 + t];

    // coalesced P store: P[q_global][kv_global], 256 B per q-row
#pragma unroll
    for (int c = 0; c < 8; ++c) {
        int flat = c * 256 + t;            // 2048 units: 128 rows x 16
        int row = flat >> 4, u = flat & 15;
        *(bf16x8*)&P[((size_t)(bb * 4096 + n0 + row)) * 4096 + m0 + u * 8] =
            *(const bf16x8*)&((char*)Pl)[row * 256 + ((u ^ (row & 7)) << 4)];
    }
}

// ------------------------------------------------------------ PV GEMM v2
// 128x128, 512 thr, 3-buffer 2-ahead counted vmcnt(4), grid (32,4,2)=1/CU.
// l-reduction FOLDED IN: prologue computes 1/l for this block's 128 rows
// from lpart (loads fully retired before staging -> vmcnt counting intact).
__global__ __launch_bounds__(512) void pv_kernel(
    const unsigned short* __restrict__ P, const unsigned short* __restrict__ vT,
    const float* __restrict__ lpart, unsigned short* __restrict__ outb, int b0)
{
    int m0 = blockIdx.x * 128, n0 = blockIdx.y * 128, bb = blockIdx.z;
    int b = b0 + bb;
    int t = threadIdx.x, l = t & 63, w = t >> 6;
    int wm = w >> 2, wn = w & 3;
    int lr = l & 15, lg = l >> 4;

    __shared__ __align__(16) unsigned short lds[49152];  // 96 KB
    __shared__ float Lp[128];
    unsigned short* As = lds;           // 3 x 8192 (128 x 64)
    unsigned short* Bs = lds + 24576;   // 3 x 8192 (128 x 64)

    // ---- folded l-reduce: 1/l for rows m0..m0+127 (fully retired before staging)
    if (t < 128) {
        float s = 0.f;
#pragma unroll
        for (int sl = 0; sl < 32; ++sl)
            s += lpart[(size_t)(bb * 32 + sl) * 4096 + m0 + t];
        Lp[t] = 1.0f / s;
    }

    const unsigned short* A_ = P + (size_t)(bb * 4096 + m0) * 4096;
    const unsigned short* B_ = vT + ((size_t)b * 512 + n0) * 4096;

    auto stage = [&](int s, int buf) {   // 4 vmem instr per thread
        int k0 = s * 64;
        unsigned short* ad = As + buf * 8192;
        unsigned short* bd = Bs + buf * 8192;
#pragma unroll
        for (int c = 0; c < 2; ++c) {
            int flat = c * 512 + t;
            int row = flat >> 3, u = flat & 7;
            g2l16(A_ + (size_t)row * 4096 + k0 + ((u ^ (row & 7)) << 3),
                  ad + (flat << 3));
        }
#pragma unroll
        for (int c = 0; c < 2; ++c) {
            int flat = c * 512 + t;
            int row = flat >> 3, u = flat & 7;
            g2l16(B_ + (size_t)row * 4096 + k0 + ((u ^ (row & 7)) << 3),
                  bd + (flat << 3));
        }
    };

    f32x4 acc[4][2];
#pragma unroll
    for (int i = 0; i < 4; ++i)
#pragma unroll
        for (int j = 0; j < 2; ++j) acc[i][j] = f32x4{0.f, 0.f, 0.f, 0.f};

    stage(0, 0);
    stage(1, 1);
    asm volatile("s_waitcnt vmcnt(4)" ::: "memory");
    __builtin_amdgcn_s_barrier();
    __builtin_amdgcn_sched_barrier(0);

    for (int s = 0; s < 64; ++s) {
        if (s + 2 < 64) stage(s + 2, (s + 2) % 3);
        const unsigned short* Al = As + (s % 3) * 8192;
        const unsigned short* Bl = Bs + (s % 3) * 8192;
        __builtin_amdgcn_s_setprio(1);
#pragma unroll
        for (int ks = 0; ks < 2; ++ks) {
            bf16x8 af[4], bfr[2];
#pragma unroll
            for (int mi = 0; mi < 4; ++mi) {
                int row = wm * 64 + mi * 16 + lr;
                af[mi] = *(const bf16x8*)&Al[(row * 8 + ((ks * 4 + lg) ^ (row & 7))) << 3];
            }
#pragma unroll
            for (int ni = 0; ni < 2; ++ni) {
                int row = wn * 32 + ni * 16 + lr;
                bfr[ni] = *(const bf16x8*)&Bl[(row * 8 + ((ks * 4 + lg) ^ (row & 7))) << 3];
            }
#pragma unroll
            for (int mi = 0; mi < 4; ++mi)
#pragma unroll
                for (int ni = 0; ni < 2; ++ni)
                    acc[mi][ni] = MFMA16(af[mi], bfr[ni], acc[mi][ni]);
        }
        __builtin_amdgcn_s_setprio(0);
        if (s < 62) asm volatile("s_waitcnt vmcnt(4) lgkmcnt(0)" ::: "memory");
        else        asm volatile("s_waitcnt vmcnt(0) lgkmcnt(0)" ::: "memory");
        __builtin_amdgcn_s_barrier();
        __builtin_amdgcn_sched_barrier(0);
    }

#pragma unroll
    for (int mi = 0; mi < 4; ++mi)
#pragma unroll
        for (int r = 0; r < 4; ++r) {
            int rloc = wm * 64 + mi * 16 + lg * 4 + r;
            int row = m0 + rloc;
            float inv = Lp[rloc];
#pragma unroll
            for (int ni = 0; ni < 2; ++ni) {
                int col = n0 + wn * 32 + ni * 16 + lr;
                outb[(size_t)(b * 4096 + row) * 512 + col] =
                    f2bf(acc[mi][ni][r] * inv);
            }
        }
}

// --------------------------------------------------------------- launcher
extern "C" void kernel_launch(void* const* d_in, const int* in_sizes, int n_in,
                              void* d_out, int out_size, void* d_ws, size_t ws_size,
                              hipStream_t stream)
{
    const float* x     = (const float*)d_in[0];
    const float* gamma = (const float*)d_in[1];
    const float* beta  = (const float*)d_in[2];
    const float* Wq = (const float*)d_in[3];
    const float* bq = (const float*)d_in[4];
    const float* Wk = (const float*)d_in[5];
    const float* bk = (const float*)d_in[6];
    const float* Wv = (const float*)d_in[7];
    const float* bv = (const float*)d_in[8];
    const float* Wp = (const float*)d_in[9];
    const float* bp = (const float*)d_in[10];
    float* out = (float*)d_out;

    unsigned short* xn    = (unsigned short*)d_ws;                 // 16384*512 (reused as attn out)
    unsigned short* wqkvt = xn + (size_t)16384 * 512;              // 1536*512
    unsigned short* wpt   = wqkvt + (size_t)1536 * 512;            // 512*512
    unsigned short* qkv   = wpt + (size_t)512 * 512;               // 16384*1536
    unsigned short* vT    = qkv + (size_t)16384 * 1536;            // 4*512*4096
    unsigned short* P     = vT + (size_t)4 * 512 * 4096;           // 2*4096*4096 (64MB)
    float* lpart = (float*)(P + (size_t)2 * 4096 * 4096);          // 64*4096 f32
    float* linv  = lpart + (size_t)128 * 4096;                     // (unused)
    float2* gstats = (float2*)(linv + 8192);                       // 1024 float2

    prep_kernel<<<dim3(5120), dim3(256), 0, stream>>>(
        x, Wq, Wk, Wv, Wp, gstats, wqkvt, wpt);
    gn_apply<<<dim3(2048), dim3(256), 0, stream>>>(x, gamma, beta, gstats, xn);
    gemm_kernel<0><<<dim3(128, 12), dim3(256), 0, stream>>>(
        xn, wqkvt, bq, bk, bv, nullptr, nullptr, qkv, nullptr);
    vtrans<<<dim3(64, 8, 4), dim3(256), 0, stream>>>(qkv, vT);

    for (int b0 = 0; b0 < 4; b0 += 2) {
        qk_kernel<<<dim3(2048), dim3(256), 0, stream>>>(qkv, P, lpart, b0);
        pv_kernel<<<dim3(32, 4, 2), dim3(512), 0, stream>>>(P, vT, lpart, xn, b0);
    }

    gemm_kernel<1><<<dim3(128, 4), dim3(256), 0, stream>>>(
        xn, wpt, nullptr, nullptr, nullptr, bp, x, nullptr, out);
}

// Round 17
// 249.978 us; speedup vs baseline: 1.1645x; 1.1645x over previous
//
#include <hip/hip_runtime.h>
#include <hip/hip_bf16.h>

typedef __attribute__((ext_vector_type(8))) short bf16x8;
typedef __attribute__((ext_vector_type(4))) float f32x4;
typedef __attribute__((ext_vector_type(4))) unsigned short u16x4;

#define MFMA16(a, b, c) __builtin_amdgcn_mfma_f32_16x16x32_bf16(a, b, c, 0, 0, 0)

#define SCALE 0.21022410381342865f /* 512^(-1/4) */

__device__ __forceinline__ unsigned short f2bf(float f) {
    union { float f; unsigned u; } v; v.f = f;
    unsigned r = v.u + 0x7FFF + ((v.u >> 16) & 1);
    return (unsigned short)(r >> 16);
}

__device__ __forceinline__ unsigned cvtpk(float lo, float hi) {
    unsigned r;
    asm("v_cvt_pk_bf16_f32 %0, %1, %2" : "=v"(r) : "v"(lo), "v"(hi));
    return r;
}

typedef __attribute__((address_space(3))) void lds_void;
typedef const __attribute__((address_space(1))) void gbl_void;
__device__ __forceinline__ void g2l16(const void* g, void* l) {
    __builtin_amdgcn_global_load_lds((gbl_void*)g, (lds_void*)l, 16, 0, 0);
}

#define PHASE_BARRIER() do { \
    asm volatile("s_waitcnt vmcnt(0) lgkmcnt(0)" ::: "memory"); \
    __builtin_amdgcn_s_barrier(); \
    __builtin_amdgcn_sched_barrier(0); \
} while (0)

#define LGKM_BARRIER() do { \
    asm volatile("s_waitcnt lgkmcnt(0)" ::: "memory"); \
    __builtin_amdgcn_s_barrier(); \
    __builtin_amdgcn_sched_barrier(0); \
} while (0)

// --------------------------------------- prep: gn_stats + weight cast/T
// grid 5120: blocks 0..4095 = wprep work, 4096..5119 = gn stats partials.
__global__ __launch_bounds__(256) void prep_kernel(
    const float* __restrict__ x,
    const float* __restrict__ Wq, const float* __restrict__ Wk,
    const float* __restrict__ Wv, const float* __restrict__ Wp,
    float2* __restrict__ gstats,
    unsigned short* __restrict__ wqkvt, unsigned short* __restrict__ wpt)
{
    __shared__ float rs_[4], rss_[4];
    if (blockIdx.x < 4096) {
        int idx = blockIdx.x * 256 + threadIdx.x; // 1,048,576 total
        if (idx < 786432) {
            int n = idx >> 9, k = idx & 511;
            int j = n >> 9, nn = n & 511;
            const float* W = (j == 0) ? Wq : (j == 1) ? Wk : Wv;
            wqkvt[idx] = f2bf(W[k * 512 + nn]);
        } else {
            int i2 = idx - 786432;
            int n = i2 >> 9, k = i2 & 511;
            wpt[i2] = f2bf(Wp[k * 512 + n]);
        }
        return;
    }
    int id = blockIdx.x - 4096;
    int b = id >> 8, rem = id & 255;
    int g = rem >> 3, sl = rem & 7;
    int t = threadIdx.x;
    const float4* xf4 = (const float4*)x;
    size_t base4 = (size_t)b * (4096 * 128) + g * 4;

    float s = 0.f, ss = 0.f;
#pragma unroll
    for (int i = 0; i < 8; ++i) {
        int flat = i * 256 + t;
        int hw = sl * 512 + (flat >> 2), c4 = flat & 3;
        float4 v = xf4[base4 + (size_t)hw * 128 + c4];
        s  += v.x + v.y + v.z + v.w;
        ss += v.x * v.x + v.y * v.y + v.z * v.z + v.w * v.w;
    }
    for (int m = 32; m >= 1; m >>= 1) { s += __shfl_xor(s, m); ss += __shfl_xor(ss, m); }
    int wv = t >> 6;
    if ((t & 63) == 0) { rs_[wv] = s; rss_[wv] = ss; }
    __syncthreads();
    if (t == 0) {
        float2 o;
        o.x = rs_[0] + rs_[1] + rs_[2] + rs_[3];
        o.y = rss_[0] + rss_[1] + rss_[2] + rss_[3];
        gstats[id] = o;
    }
}

// ------------------------------------------------------- GroupNorm apply
__global__ __launch_bounds__(256) void gn_apply(
    const float* __restrict__ x, const float* __restrict__ gamma,
    const float* __restrict__ beta, const float2* __restrict__ gstats,
    unsigned short* __restrict__ xn)
{
    int id = blockIdx.x;
    int b = id >> 9, rem = id & 511;
    int g = rem >> 4, sl = rem & 15;
    int t = threadIdx.x;

    float s = 0.f, ss = 0.f;
#pragma unroll
    for (int i = 0; i < 8; ++i) {
        float2 p = gstats[(b * 32 + g) * 8 + i];
        s += p.x; ss += p.y;
    }
    float mean = s * (1.f / 65536.f);
    float var  = ss * (1.f / 65536.f) - mean * mean;
    float rstd = rsqrtf(var + 1e-6f);

    const float4* xf4 = (const float4*)x;
    const float4* g4 = (const float4*)gamma;
    const float4* b4 = (const float4*)beta;
    size_t base4 = (size_t)b * (4096 * 128) + g * 4;
#pragma unroll
    for (int i = 0; i < 4; ++i) {
        int flat = i * 256 + t;
        int hw = sl * 256 + (flat >> 2), c4 = flat & 3;
        float4 v  = xf4[base4 + (size_t)hw * 128 + c4];
        float4 gm = g4[g * 4 + c4], bt = b4[g * 4 + c4];
        u16x4 o;
        o.x = f2bf((v.x - mean) * rstd * gm.x + bt.x);
        o.y = f2bf((v.y - mean) * rstd * gm.y + bt.y);
        o.z = f2bf((v.z - mean) * rstd * gm.z + bt.z);
        o.w = f2bf((v.w - mean) * rstd * gm.w + bt.w);
        *(u16x4*)&xn[(size_t)(b * 4096 + hw) * 512 + g * 16 + c4 * 4] = o;
    }
}

// ------------------------------------------------------------- bf16 GEMM v2
template <int MODE>
__global__ __launch_bounds__(256, 4) void gemm_kernel(
    const unsigned short* __restrict__ A, const unsigned short* __restrict__ Bt,
    const float* __restrict__ bias_q, const float* __restrict__ bias_k,
    const float* __restrict__ bias_v, const float* __restrict__ bias_p,
    const float* __restrict__ resid,
    unsigned short* __restrict__ Cbf, float* __restrict__ Cf)
{
    int m0 = blockIdx.x * 128;
    int n0 = blockIdx.y * 128;
    int t = threadIdx.x;
    int l = t & 63, w = t >> 6;
    int wm = w >> 1, wn = w & 1;
    int lr = l & 15, lg = l >> 4;

    __shared__ __align__(16) unsigned short lds[16384];  // 32 KB
    unsigned short* As = lds;
    unsigned short* Bs = lds + 8192;

    const unsigned short* A_ = A + (size_t)m0 * 512;
    const unsigned short* B_ = Bt + (size_t)n0 * 512;

    auto stage = [&](int s) {
        int k0 = s * 64;
#pragma unroll
        for (int c = 0; c < 4; ++c) {
            int flat = c * 256 + t;
            int row = flat >> 3, u = flat & 7;
            g2l16(A_ + (size_t)row * 512 + k0 + ((u ^ (row & 7)) << 3),
                  As + (flat << 3));
        }
#pragma unroll
        for (int c = 0; c < 4; ++c) {
            int flat = c * 256 + t;
            int row = flat >> 3, u = flat & 7;
            g2l16(B_ + (size_t)row * 512 + k0 + ((u ^ (row & 7)) << 3),
                  Bs + (flat << 3));
        }
    };

    f32x4 acc[4][4];
#pragma unroll
    for (int i = 0; i < 4; ++i)
#pragma unroll
        for (int j = 0; j < 4; ++j) acc[i][j] = f32x4{0.f, 0.f, 0.f, 0.f};

    for (int s = 0; s < 8; ++s) {
        if (s) LGKM_BARRIER();
        stage(s);
        PHASE_BARRIER();
        __builtin_amdgcn_s_setprio(1);
#pragma unroll
        for (int ks = 0; ks < 2; ++ks) {
            bf16x8 af[4], bfr[4];
#pragma unroll
            for (int mi = 0; mi < 4; ++mi) {
                int row = wm * 64 + mi * 16 + lr;
                af[mi] = *(const bf16x8*)&As[(row * 8 + ((ks * 4 + lg) ^ (row & 7))) << 3];
            }
#pragma unroll
            for (int ni = 0; ni < 4; ++ni) {
                int row = wn * 64 + ni * 16 + lr;
                bfr[ni] = *(const bf16x8*)&Bs[(row * 8 + ((ks * 4 + lg) ^ (row & 7))) << 3];
            }
#pragma unroll
            for (int mi = 0; mi < 4; ++mi)
#pragma unroll
                for (int ni = 0; ni < 4; ++ni)
                    acc[mi][ni] = MFMA16(af[mi], bfr[ni], acc[mi][ni]);
        }
        __builtin_amdgcn_s_setprio(0);
    }

#pragma unroll
    for (int mi = 0; mi < 4; ++mi)
#pragma unroll
        for (int ni = 0; ni < 4; ++ni)
#pragma unroll
            for (int r = 0; r < 4; ++r) {
                int row = m0 + wm * 64 + mi * 16 + lg * 4 + r;
                int col = n0 + wn * 64 + ni * 16 + lr;
                float val = acc[mi][ni][r];
                if (MODE == 0) {
                    float bias, scl;
                    if (col < 512)       { bias = bias_q[col];        scl = SCALE; }
                    else if (col < 1024) { bias = bias_k[col - 512];  scl = SCALE; }
                    else                 { bias = bias_v[col - 1024]; scl = 1.0f;  }
                    Cbf[(size_t)row * 1536 + col] = f2bf((val + bias) * scl);
                } else {
                    Cf[(size_t)row * 512 + col] =
                        val + bias_p[col] + resid[(size_t)row * 512 + col];
                }
            }
}

// ------------------------------------------------ V transpose to [b][d][n]
__global__ __launch_bounds__(256) void vtrans(
    const unsigned short* __restrict__ qkv, unsigned short* __restrict__ vT)
{
    int n0 = blockIdx.x * 64, d0 = blockIdx.y * 64, b = blockIdx.z;
    int t = threadIdx.x;
    __shared__ unsigned short tile[64][72];
    for (int c = 0; c < 2; ++c) {
        int flat = c * 256 + t;
        int r = flat >> 3, cc = (flat & 7) * 8;
        *(bf16x8*)&tile[r][cc] =
            *(const bf16x8*)&qkv[(size_t)(b * 4096 + n0 + r) * 1536 + 1024 + d0 + cc];
    }
    __syncthreads();
    for (int c = 0; c < 2; ++c) {
        int flat = c * 256 + t;
        int dr = flat >> 3, nc = (flat & 7) * 8;
        bf16x8 v;
        for (int j = 0; j < 8; ++j) v[j] = (short)tile[nc + j][dr];
        *(bf16x8*)&vT[((size_t)b * 512 + d0 + dr) * 4096 + n0 + nc] = v;
    }
}

// ------------------------------------------------------------ QK^T + exp v4
__global__ __launch_bounds__(256, 4) void qk_kernel(
    const unsigned short* __restrict__ qkv, unsigned short* __restrict__ P,
    float* __restrict__ lpart, int b0)
{
    int W = blockIdx.x;
    int xcd = W & 7, i = W >> 3;
    int bb = xcd >> 2;
    int nb = (xcd & 3) * 8 + (i & 7);   // q-block
    int mb = i >> 3;                    // kv-block
    int m0 = mb * 128, n0 = nb * 128;
    int b = b0 + bb;

    int t = threadIdx.x, l = t & 63, w = t >> 6;
    int wm = w >> 1, wn = w & 1;
    int lr = l & 15, lg = l >> 4;

    __shared__ __align__(16) unsigned short lds[16896];  // 33 KB
    unsigned short* As = lds;             // K tile 128x64 (kv rows)
    unsigned short* Bs = lds + 8192;      // Q tile 128x64 (q rows)
    float* Lw = (float*)(lds + 16384);    // 2 x 128 row-sum halves

    const unsigned short* A_ = qkv + (size_t)(b * 4096 + m0) * 1536 + 512;  // K
    const unsigned short* B_ = qkv + (size_t)(b * 4096 + n0) * 1536;        // Q

    auto stage = [&](int s) {
        int k0 = s * 64;
#pragma unroll
        for (int c = 0; c < 4; ++c) {
            int flat = c * 256 + t;       // 1024 units: 128 rows x 8
            int row = flat >> 3, u = flat & 7;
            g2l16(A_ + (size_t)row * 1536 + k0 + ((u ^ (row & 7)) << 3),
                  As + (flat << 3));
        }
#pragma unroll
        for (int c = 0; c < 4; ++c) {
            int flat = c * 256 + t;
            int row = flat >> 3, u = flat & 7;
            g2l16(B_ + (size_t)row * 1536 + k0 + ((u ^ (row & 7)) << 3),
                  Bs + (flat << 3));
        }
    };

    f32x4 acc[4][4];
#pragma unroll
    for (int mi = 0; mi < 4; ++mi)
#pragma unroll
        for (int ni = 0; ni < 4; ++ni) acc[mi][ni] = f32x4{0.f, 0.f, 0.f, 0.f};

    for (int s = 0; s < 8; ++s) {
        if (s) LGKM_BARRIER();             // all reads of buf retired
        stage(s);
        PHASE_BARRIER();                   // DMA landed
        __builtin_amdgcn_s_setprio(1);
#pragma unroll
        for (int ks = 0; ks < 2; ++ks) {
            bf16x8 af[4], bfr[4];
#pragma unroll
            for (int mi = 0; mi < 4; ++mi) {
                int row = wm * 64 + mi * 16 + lr;
                af[mi] = *(const bf16x8*)&As[(row * 8 + ((ks * 4 + lg) ^ (row & 7))) << 3];
            }
#pragma unroll
            for (int ni = 0; ni < 4; ++ni) {
                int row = wn * 64 + ni * 16 + lr;
                bfr[ni] = *(const bf16x8*)&Bs[(row * 8 + ((ks * 4 + lg) ^ (row & 7))) << 3];
            }
#pragma unroll
            for (int mi = 0; mi < 4; ++mi)
#pragma unroll
                for (int ni = 0; ni < 4; ++ni)
                    acc[mi][ni] = MFMA16(af[mi], bfr[ni], acc[mi][ni]);
        }
        __builtin_amdgcn_s_setprio(0);
    }
    LGKM_BARRIER();   // last compute's LDS reads retired -> buffers reusable

    // ---- epilogue: exp + in-lane row sums + packed P writes (S^T layout)
    unsigned short* Pl = lds;             // 128 q x 128 kv = 32 KB overlay
    {
        float sums[4] = {0.f, 0.f, 0.f, 0.f};
#pragma unroll
        for (int mi = 0; mi < 4; ++mi) {
            int u = wm * 8 + mi * 2 + (lg >> 1);   // 16B unit (16/row)
            int half = lg & 1;
#pragma unroll
            for (int ni = 0; ni < 4; ++ni) {
                float p0 = __expf(acc[mi][ni][0]);
                float p1 = __expf(acc[mi][ni][1]);
                float p2 = __expf(acc[mi][ni][2]);
                float p3 = __expf(acc[mi][ni][3]);
                sums[ni] += p0 + p1 + p2 + p3;
                int q = wn * 64 + ni * 16 + lr;
                unsigned* dst = (unsigned*)&((char*)Pl)[
                    q * 256 + ((u ^ (q & 7)) << 4) + (half << 3)];
                dst[0] = cvtpk(p0, p1);
                dst[1] = cvtpk(p2, p3);
            }
        }
#pragma unroll
        for (int ni = 0; ni < 4; ++ni) {
            float v = sums[ni];
            v += __shfl_xor(v, 16);
            v += __shfl_xor(v, 32);
            if (lg == 0) Lw[wm * 128 + wn * 64 + ni * 16 + lr] = v;
        }
    }
    LGKM_BARRIER();

    if (t < 128)
        lpart[(size_t)(bb * 32 + mb) * 4096 + n0 + t] = Lw[t] + Lw[128 + t];

    // coalesced P store: P[q_global][kv_global], 256 B per q-row
#pragma unroll
    for (int c = 0; c < 8; ++c) {
        int flat = c * 256 + t;            // 2048 units: 128 rows x 16
        int row = flat >> 4, u = flat & 15;
        *(bf16x8*)&P[((size_t)(bb * 4096 + n0 + row)) * 4096 + m0 + u * 8] =
            *(const bf16x8*)&((char*)Pl)[row * 256 + ((u ^ (row & 7)) << 4)];
    }
}

// ----------------------------------------------------- l reduce (32 slices)
__global__ __launch_bounds__(256) void lred_kernel(
    const float* __restrict__ lpart, float* __restrict__ lsum)
{
    int rr = blockIdx.x * 256 + threadIdx.x;  // 0..8191
    int bb = rr >> 12, r = rr & 4095;
    float s = 0.f;
#pragma unroll
    for (int sl = 0; sl < 32; ++sl)
        s += lpart[(size_t)(bb * 32 + sl) * 4096 + r];
    lsum[rr] = 1.0f / s;
}

// ------------------------------------------------------------ PV GEMM v2
// 128x128, 512 thr, 3-buffer 2-ahead counted vmcnt(4), grid (32,4,2)=1/CU.
// (r16's folded l-reduce regressed this kernel ~25 µs/dispatch — the extra
//  in-flight prologue loads broke the hand-counted vmcnt pipeline. Keep the
//  pipeline pristine: linv comes from the separate lred kernel.)
__global__ __launch_bounds__(512) void pv_kernel(
    const unsigned short* __restrict__ P, const unsigned short* __restrict__ vT,
    const float* __restrict__ linv, unsigned short* __restrict__ outb, int b0)
{
    int m0 = blockIdx.x * 128, n0 = blockIdx.y * 128, bb = blockIdx.z;
    int b = b0 + bb;
    int t = threadIdx.x, l = t & 63, w = t >> 6;
    int wm = w >> 2, wn = w & 3;
    int lr = l & 15, lg = l >> 4;

    __shared__ __align__(16) unsigned short lds[49152];  // 96 KB
    unsigned short* As = lds;           // 3 x 8192 (128 x 64)
    unsigned short* Bs = lds + 24576;   // 3 x 8192 (128 x 64)

    const unsigned short* A_ = P + (size_t)(bb * 4096 + m0) * 4096;
    const unsigned short* B_ = vT + ((size_t)b * 512 + n0) * 4096;

    auto stage = [&](int s, int buf) {   // 4 vmem instr per thread
        int k0 = s * 64;
        unsigned short* ad = As + buf * 8192;
        unsigned short* bd = Bs + buf * 8192;
#pragma unroll
        for (int c = 0; c < 2; ++c) {
            int flat = c * 512 + t;
            int row = flat >> 3, u = flat & 7;
            g2l16(A_ + (size_t)row * 4096 + k0 + ((u ^ (row & 7)) << 3),
                  ad + (flat << 3));
        }
#pragma unroll
        for (int c = 0; c < 2; ++c) {
            int flat = c * 512 + t;
            int row = flat >> 3, u = flat & 7;
            g2l16(B_ + (size_t)row * 4096 + k0 + ((u ^ (row & 7)) << 3),
                  bd + (flat << 3));
        }
    };

    f32x4 acc[4][2];
#pragma unroll
    for (int i = 0; i < 4; ++i)
#pragma unroll
        for (int j = 0; j < 2; ++j) acc[i][j] = f32x4{0.f, 0.f, 0.f, 0.f};

    stage(0, 0);
    stage(1, 1);
    asm volatile("s_waitcnt vmcnt(4)" ::: "memory");
    __builtin_amdgcn_s_barrier();
    __builtin_amdgcn_sched_barrier(0);

    for (int s = 0; s < 64; ++s) {
        if (s + 2 < 64) stage(s + 2, (s + 2) % 3);
        const unsigned short* Al = As + (s % 3) * 8192;
        const unsigned short* Bl = Bs + (s % 3) * 8192;
        __builtin_amdgcn_s_setprio(1);
#pragma unroll
        for (int ks = 0; ks < 2; ++ks) {
            bf16x8 af[4], bfr[2];
#pragma unroll
            for (int mi = 0; mi < 4; ++mi) {
                int row = wm * 64 + mi * 16 + lr;
                af[mi] = *(const bf16x8*)&Al[(row * 8 + ((ks * 4 + lg) ^ (row & 7))) << 3];
            }
#pragma unroll
            for (int ni = 0; ni < 2; ++ni) {
                int row = wn * 32 + ni * 16 + lr;
                bfr[ni] = *(const bf16x8*)&Bl[(row * 8 + ((ks * 4 + lg) ^ (row & 7))) << 3];
            }
#pragma unroll
            for (int mi = 0; mi < 4; ++mi)
#pragma unroll
                for (int ni = 0; ni < 2; ++ni)
                    acc[mi][ni] = MFMA16(af[mi], bfr[ni], acc[mi][ni]);
        }
        __builtin_amdgcn_s_setprio(0);
        if (s < 62) asm volatile("s_waitcnt vmcnt(4) lgkmcnt(0)" ::: "memory");
        else        asm volatile("s_waitcnt vmcnt(0) lgkmcnt(0)" ::: "memory");
        __builtin_amdgcn_s_barrier();
        __builtin_amdgcn_sched_barrier(0);
    }

#pragma unroll
    for (int mi = 0; mi < 4; ++mi)
#pragma unroll
        for (int r = 0; r < 4; ++r) {
            int row = m0 + wm * 64 + mi * 16 + lg * 4 + r;
            float inv = linv[bb * 4096 + row];
#pragma unroll
            for (int ni = 0; ni < 2; ++ni) {
                int col = n0 + wn * 32 + ni * 16 + lr;
                outb[(size_t)(b * 4096 + row) * 512 + col] =
                    f2bf(acc[mi][ni][r] * inv);
            }
        }
}

// --------------------------------------------------------------- launcher
extern "C" void kernel_launch(void* const* d_in, const int* in_sizes, int n_in,
                              void* d_out, int out_size, void* d_ws, size_t ws_size,
                              hipStream_t stream)
{
    const float* x     = (const float*)d_in[0];
    const float* gamma = (const float*)d_in[1];
    const float* beta  = (const float*)d_in[2];
    const float* Wq = (const float*)d_in[3];
    const float* bq = (const float*)d_in[4];
    const float* Wk = (const float*)d_in[5];
    const float* bk = (const float*)d_in[6];
    const float* Wv = (const float*)d_in[7];
    const float* bv = (const float*)d_in[8];
    const float* Wp = (const float*)d_in[9];
    const float* bp = (const float*)d_in[10];
    float* out = (float*)d_out;

    unsigned short* xn    = (unsigned short*)d_ws;                 // 16384*512 (reused as attn out)
    unsigned short* wqkvt = xn + (size_t)16384 * 512;              // 1536*512
    unsigned short* wpt   = wqkvt + (size_t)1536 * 512;            // 512*512
    unsigned short* qkv   = wpt + (size_t)512 * 512;               // 16384*1536
    unsigned short* vT    = qkv + (size_t)16384 * 1536;            // 4*512*4096
    unsigned short* P     = vT + (size_t)4 * 512 * 4096;           // 2*4096*4096 (64MB)
    float* lpart = (float*)(P + (size_t)2 * 4096 * 4096);          // 64*4096 f32
    float* linv  = lpart + (size_t)128 * 4096;                     // 8192 f32
    float2* gstats = (float2*)(linv + 8192);                       // 1024 float2

    prep_kernel<<<dim3(5120), dim3(256), 0, stream>>>(
        x, Wq, Wk, Wv, Wp, gstats, wqkvt, wpt);
    gn_apply<<<dim3(2048), dim3(256), 0, stream>>>(x, gamma, beta, gstats, xn);
    gemm_kernel<0><<<dim3(128, 12), dim3(256), 0, stream>>>(
        xn, wqkvt, bq, bk, bv, nullptr, nullptr, qkv, nullptr);
    vtrans<<<dim3(64, 8, 4), dim3(256), 0, stream>>>(qkv, vT);

    for (int b0 = 0; b0 < 4; b0 += 2) {
        qk_kernel<<<dim3(2048), dim3(256), 0, stream>>>(qkv, P, lpart, b0);
        lred_kernel<<<dim3(32), dim3(256), 0, stream>>>(lpart, linv);
        pv_kernel<<<dim3(32, 4, 2), dim3(512), 0, stream>>>(P, vT, linv, xn, b0);
    }

    gemm_kernel<1><<<dim3(128, 4), dim3(256), 0, stream>>>(
        xn, wpt, nullptr, nullptr, nullptr, bp, x, nullptr, out);
}

// Round 18
// 242.201 us; speedup vs baseline: 1.2018x; 1.0321x over previous
//
#include <hip/hip_runtime.h>
#include <hip/hip_bf16.h>

typedef __attribute__((ext_vector_type(8))) short bf16x8;
typedef __attribute__((ext_vector_type(4))) float f32x4;
typedef __attribute__((ext_vector_type(4))) unsigned short u16x4;

#define MFMA16(a, b, c) __builtin_amdgcn_mfma_f32_16x16x32_bf16(a, b, c, 0, 0, 0)

#define SCALE 0.21022410381342865f /* 512^(-1/4) */

__device__ __forceinline__ unsigned short f2bf(float f) {
    union { float f; unsigned u; } v; v.f = f;
    unsigned r = v.u + 0x7FFF + ((v.u >> 16) & 1);
    return (unsigned short)(r >> 16);
}

__device__ __forceinline__ unsigned cvtpk(float lo, float hi) {
    unsigned r;
    asm("v_cvt_pk_bf16_f32 %0, %1, %2" : "=v"(r) : "v"(lo), "v"(hi));
    return r;
}

typedef __attribute__((address_space(3))) void lds_void;
typedef const __attribute__((address_space(1))) void gbl_void;
__device__ __forceinline__ void g2l16(const void* g, void* l) {
    __builtin_amdgcn_global_load_lds((gbl_void*)g, (lds_void*)l, 16, 0, 0);
}

#define PHASE_BARRIER() do { \
    asm volatile("s_waitcnt vmcnt(0) lgkmcnt(0)" ::: "memory"); \
    __builtin_amdgcn_s_barrier(); \
    __builtin_amdgcn_sched_barrier(0); \
} while (0)

#define LGKM_BARRIER() do { \
    asm volatile("s_waitcnt lgkmcnt(0)" ::: "memory"); \
    __builtin_amdgcn_s_barrier(); \
    __builtin_amdgcn_sched_barrier(0); \
} while (0)

// --------------------------------------- prep: gn_stats + weight cast/T
// grid 5120: blocks 0..4095 = wprep work, 4096..5119 = gn stats partials.
__global__ __launch_bounds__(256) void prep_kernel(
    const float* __restrict__ x,
    const float* __restrict__ Wq, const float* __restrict__ Wk,
    const float* __restrict__ Wv, const float* __restrict__ Wp,
    float2* __restrict__ gstats,
    unsigned short* __restrict__ wqkvt, unsigned short* __restrict__ wpt)
{
    __shared__ float rs_[4], rss_[4];
    if (blockIdx.x < 4096) {
        int idx = blockIdx.x * 256 + threadIdx.x; // 1,048,576 total
        if (idx < 786432) {
            int n = idx >> 9, k = idx & 511;
            int j = n >> 9, nn = n & 511;
            const float* W = (j == 0) ? Wq : (j == 1) ? Wk : Wv;
            wqkvt[idx] = f2bf(W[k * 512 + nn]);
        } else {
            int i2 = idx - 786432;
            int n = i2 >> 9, k = i2 & 511;
            wpt[i2] = f2bf(Wp[k * 512 + n]);
        }
        return;
    }
    int id = blockIdx.x - 4096;
    int b = id >> 8, rem = id & 255;
    int g = rem >> 3, sl = rem & 7;
    int t = threadIdx.x;
    const float4* xf4 = (const float4*)x;
    size_t base4 = (size_t)b * (4096 * 128) + g * 4;

    float s = 0.f, ss = 0.f;
#pragma unroll
    for (int i = 0; i < 8; ++i) {
        int flat = i * 256 + t;
        int hw = sl * 512 + (flat >> 2), c4 = flat & 3;
        float4 v = xf4[base4 + (size_t)hw * 128 + c4];
        s  += v.x + v.y + v.z + v.w;
        ss += v.x * v.x + v.y * v.y + v.z * v.z + v.w * v.w;
    }
    for (int m = 32; m >= 1; m >>= 1) { s += __shfl_xor(s, m); ss += __shfl_xor(ss, m); }
    int wv = t >> 6;
    if ((t & 63) == 0) { rs_[wv] = s; rss_[wv] = ss; }
    __syncthreads();
    if (t == 0) {
        float2 o;
        o.x = rs_[0] + rs_[1] + rs_[2] + rs_[3];
        o.y = rss_[0] + rss_[1] + rss_[2] + rss_[3];
        gstats[id] = o;
    }
}

// ------------------------------------------------------- GroupNorm apply
__global__ __launch_bounds__(256) void gn_apply(
    const float* __restrict__ x, const float* __restrict__ gamma,
    const float* __restrict__ beta, const float2* __restrict__ gstats,
    unsigned short* __restrict__ xn)
{
    int id = blockIdx.x;
    int b = id >> 9, rem = id & 511;
    int g = rem >> 4, sl = rem & 15;
    int t = threadIdx.x;

    float s = 0.f, ss = 0.f;
#pragma unroll
    for (int i = 0; i < 8; ++i) {
        float2 p = gstats[(b * 32 + g) * 8 + i];
        s += p.x; ss += p.y;
    }
    float mean = s * (1.f / 65536.f);
    float var  = ss * (1.f / 65536.f) - mean * mean;
    float rstd = rsqrtf(var + 1e-6f);

    const float4* xf4 = (const float4*)x;
    const float4* g4 = (const float4*)gamma;
    const float4* b4 = (const float4*)beta;
    size_t base4 = (size_t)b * (4096 * 128) + g * 4;
#pragma unroll
    for (int i = 0; i < 4; ++i) {
        int flat = i * 256 + t;
        int hw = sl * 256 + (flat >> 2), c4 = flat & 3;
        float4 v  = xf4[base4 + (size_t)hw * 128 + c4];
        float4 gm = g4[g * 4 + c4], bt = b4[g * 4 + c4];
        u16x4 o;
        o.x = f2bf((v.x - mean) * rstd * gm.x + bt.x);
        o.y = f2bf((v.y - mean) * rstd * gm.y + bt.y);
        o.z = f2bf((v.z - mean) * rstd * gm.z + bt.z);
        o.w = f2bf((v.w - mean) * rstd * gm.w + bt.w);
        *(u16x4*)&xn[(size_t)(b * 4096 + hw) * 512 + g * 16 + c4 * 4] = o;
    }
}

// ------------------------------------------------------------- bf16 GEMM v3
// MODE 0 with blockIdx.y >= 8 = V tile: instead of storing to qkv, bias-add,
// repack [d][tok] in a 32 KB unit-swizzled LDS overlay (qk's proven pattern),
// and store COALESCED directly to vT -> vtrans kernel eliminated.
template <int MODE>
__global__ __launch_bounds__(256, 4) void gemm_kernel(
    const unsigned short* __restrict__ A, const unsigned short* __restrict__ Bt,
    const float* __restrict__ bias_q, const float* __restrict__ bias_k,
    const float* __restrict__ bias_v, const float* __restrict__ bias_p,
    const float* __restrict__ resid,
    unsigned short* __restrict__ Cbf, float* __restrict__ Cf,
    unsigned short* __restrict__ vTo)
{
    int m0 = blockIdx.x * 128;
    int n0 = blockIdx.y * 128;
    int t = threadIdx.x;
    int l = t & 63, w = t >> 6;
    int wm = w >> 1, wn = w & 1;
    int lr = l & 15, lg = l >> 4;

    __shared__ __align__(16) unsigned short lds[16384];  // 32 KB
    unsigned short* As = lds;
    unsigned short* Bs = lds + 8192;

    const unsigned short* A_ = A + (size_t)m0 * 512;
    const unsigned short* B_ = Bt + (size_t)n0 * 512;

    auto stage = [&](int s) {
        int k0 = s * 64;
#pragma unroll
        for (int c = 0; c < 4; ++c) {
            int flat = c * 256 + t;
            int row = flat >> 3, u = flat & 7;
            g2l16(A_ + (size_t)row * 512 + k0 + ((u ^ (row & 7)) << 3),
                  As + (flat << 3));
        }
#pragma unroll
        for (int c = 0; c < 4; ++c) {
            int flat = c * 256 + t;
            int row = flat >> 3, u = flat & 7;
            g2l16(B_ + (size_t)row * 512 + k0 + ((u ^ (row & 7)) << 3),
                  Bs + (flat << 3));
        }
    };

    f32x4 acc[4][4];
#pragma unroll
    for (int i = 0; i < 4; ++i)
#pragma unroll
        for (int j = 0; j < 4; ++j) acc[i][j] = f32x4{0.f, 0.f, 0.f, 0.f};

    for (int s = 0; s < 8; ++s) {
        if (s) LGKM_BARRIER();
        stage(s);
        PHASE_BARRIER();
        __builtin_amdgcn_s_setprio(1);
#pragma unroll
        for (int ks = 0; ks < 2; ++ks) {
            bf16x8 af[4], bfr[4];
#pragma unroll
            for (int mi = 0; mi < 4; ++mi) {
                int row = wm * 64 + mi * 16 + lr;
                af[mi] = *(const bf16x8*)&As[(row * 8 + ((ks * 4 + lg) ^ (row & 7))) << 3];
            }
#pragma unroll
            for (int ni = 0; ni < 4; ++ni) {
                int row = wn * 64 + ni * 16 + lr;
                bfr[ni] = *(const bf16x8*)&Bs[(row * 8 + ((ks * 4 + lg) ^ (row & 7))) << 3];
            }
#pragma unroll
            for (int mi = 0; mi < 4; ++mi)
#pragma unroll
                for (int ni = 0; ni < 4; ++ni)
                    acc[mi][ni] = MFMA16(af[mi], bfr[ni], acc[mi][ni]);
        }
        __builtin_amdgcn_s_setprio(0);
    }

    if (MODE == 0 && blockIdx.y >= 8) {
        // ---- V tile: bias + transpose-repack via LDS, store to vT
        LGKM_BARRIER();   // last compute's LDS reads retired -> overlay safe
        unsigned short* Tl = lds;   // 128 d x 128 tok (unit-swizzled), 32 KB
#pragma unroll
        for (int ni = 0; ni < 4; ++ni) {
            int d_loc = wn * 64 + ni * 16 + lr;
            float bias = bias_v[n0 - 1024 + d_loc];
#pragma unroll
            for (int mi = 0; mi < 4; ++mi) {
                int tok = wm * 64 + mi * 16 + lg * 4;   // +r, 4 contiguous
                int u = tok >> 3, off = tok & 7;        // off in {0,4}
                unsigned* dst = (unsigned*)&((char*)Tl)[
                    d_loc * 256 + ((u ^ (d_loc & 7)) << 4) + off * 2];
                dst[0] = cvtpk(acc[mi][ni][0] + bias, acc[mi][ni][1] + bias);
                dst[1] = cvtpk(acc[mi][ni][2] + bias, acc[mi][ni][3] + bias);
            }
        }
        LGKM_BARRIER();
        int b = m0 >> 12, nl0 = m0 & 4095;
        int d0 = n0 - 1024;
#pragma unroll
        for (int c = 0; c < 8; ++c) {
            int flat = c * 256 + t;        // 2048 units: 128 d-rows x 16
            int row = flat >> 4, u = flat & 15;
            *(bf16x8*)&vTo[((size_t)(b * 512 + d0 + row)) * 4096 + nl0 + u * 8] =
                *(const bf16x8*)&((char*)Tl)[row * 256 + ((u ^ (row & 7)) << 4)];
        }
        return;
    }

#pragma unroll
    for (int mi = 0; mi < 4; ++mi)
#pragma unroll
        for (int ni = 0; ni < 4; ++ni)
#pragma unroll
            for (int r = 0; r < 4; ++r) {
                int row = m0 + wm * 64 + mi * 16 + lg * 4 + r;
                int col = n0 + wn * 64 + ni * 16 + lr;
                float val = acc[mi][ni][r];
                if (MODE == 0) {
                    float bias = (col < 512) ? bias_q[col] : bias_k[col - 512];
                    Cbf[(size_t)row * 1536 + col] = f2bf((val + bias) * SCALE);
                } else {
                    Cf[(size_t)row * 512 + col] =
                        val + bias_p[col] + resid[(size_t)row * 512 + col];
                }
            }
}

// ------------------------------------------------------------ QK^T + exp v4
__global__ __launch_bounds__(256, 4) void qk_kernel(
    const unsigned short* __restrict__ qkv, unsigned short* __restrict__ P,
    float* __restrict__ lpart, int b0)
{
    int W = blockIdx.x;
    int xcd = W & 7, i = W >> 3;
    int bb = xcd >> 2;
    int nb = (xcd & 3) * 8 + (i & 7);   // q-block
    int mb = i >> 3;                    // kv-block
    int m0 = mb * 128, n0 = nb * 128;
    int b = b0 + bb;

    int t = threadIdx.x, l = t & 63, w = t >> 6;
    int wm = w >> 1, wn = w & 1;
    int lr = l & 15, lg = l >> 4;

    __shared__ __align__(16) unsigned short lds[16896];  // 33 KB
    unsigned short* As = lds;             // K tile 128x64 (kv rows)
    unsigned short* Bs = lds + 8192;      // Q tile 128x64 (q rows)
    float* Lw = (float*)(lds + 16384);    // 2 x 128 row-sum halves

    const unsigned short* A_ = qkv + (size_t)(b * 4096 + m0) * 1536 + 512;  // K
    const unsigned short* B_ = qkv + (size_t)(b * 4096 + n0) * 1536;        // Q

    auto stage = [&](int s) {
        int k0 = s * 64;
#pragma unroll
        for (int c = 0; c < 4; ++c) {
            int flat = c * 256 + t;       // 1024 units: 128 rows x 8
            int row = flat >> 3, u = flat & 7;
            g2l16(A_ + (size_t)row * 1536 + k0 + ((u ^ (row & 7)) << 3),
                  As + (flat << 3));
        }
#pragma unroll
        for (int c = 0; c < 4; ++c) {
            int flat = c * 256 + t;
            int row = flat >> 3, u = flat & 7;
            g2l16(B_ + (size_t)row * 1536 + k0 + ((u ^ (row & 7)) << 3),
                  Bs + (flat << 3));
        }
    };

    f32x4 acc[4][4];
#pragma unroll
    for (int mi = 0; mi < 4; ++mi)
#pragma unroll
        for (int ni = 0; ni < 4; ++ni) acc[mi][ni] = f32x4{0.f, 0.f, 0.f, 0.f};

    for (int s = 0; s < 8; ++s) {
        if (s) LGKM_BARRIER();             // all reads of buf retired
        stage(s);
        PHASE_BARRIER();                   // DMA landed
        __builtin_amdgcn_s_setprio(1);
#pragma unroll
        for (int ks = 0; ks < 2; ++ks) {
            bf16x8 af[4], bfr[4];
#pragma unroll
            for (int mi = 0; mi < 4; ++mi) {
                int row = wm * 64 + mi * 16 + lr;
                af[mi] = *(const bf16x8*)&As[(row * 8 + ((ks * 4 + lg) ^ (row & 7))) << 3];
            }
#pragma unroll
            for (int ni = 0; ni < 4; ++ni) {
                int row = wn * 64 + ni * 16 + lr;
                bfr[ni] = *(const bf16x8*)&Bs[(row * 8 + ((ks * 4 + lg) ^ (row & 7))) << 3];
            }
#pragma unroll
            for (int mi = 0; mi < 4; ++mi)
#pragma unroll
                for (int ni = 0; ni < 4; ++ni)
                    acc[mi][ni] = MFMA16(af[mi], bfr[ni], acc[mi][ni]);
        }
        __builtin_amdgcn_s_setprio(0);
    }
    LGKM_BARRIER();   // last compute's LDS reads retired -> buffers reusable

    // ---- epilogue: exp + in-lane row sums + packed P writes (S^T layout)
    unsigned short* Pl = lds;             // 128 q x 128 kv = 32 KB overlay
    {
        float sums[4] = {0.f, 0.f, 0.f, 0.f};
#pragma unroll
        for (int mi = 0; mi < 4; ++mi) {
            int u = wm * 8 + mi * 2 + (lg >> 1);   // 16B unit (16/row)
            int half = lg & 1;
#pragma unroll
            for (int ni = 0; ni < 4; ++ni) {
                float p0 = __expf(acc[mi][ni][0]);
                float p1 = __expf(acc[mi][ni][1]);
                float p2 = __expf(acc[mi][ni][2]);
                float p3 = __expf(acc[mi][ni][3]);
                sums[ni] += p0 + p1 + p2 + p3;
                int q = wn * 64 + ni * 16 + lr;
                unsigned* dst = (unsigned*)&((char*)Pl)[
                    q * 256 + ((u ^ (q & 7)) << 4) + (half << 3)];
                dst[0] = cvtpk(p0, p1);
                dst[1] = cvtpk(p2, p3);
            }
        }
#pragma unroll
        for (int ni = 0; ni < 4; ++ni) {
            float v = sums[ni];
            v += __shfl_xor(v, 16);
            v += __shfl_xor(v, 32);
            if (lg == 0) Lw[wm * 128 + wn * 64 + ni * 16 + lr] = v;
        }
    }
    LGKM_BARRIER();

    if (t < 128)
        lpart[(size_t)(bb * 32 + mb) * 4096 + n0 + t] = Lw[t] + Lw[128 + t];

    // coalesced P store: P[q_global][kv_global], 256 B per q-row
#pragma unroll
    for (int c = 0; c < 8; ++c) {
        int flat = c * 256 + t;            // 2048 units: 128 rows x 16
        int row = flat >> 4, u = flat & 15;
        *(bf16x8*)&P[((size_t)(bb * 4096 + n0 + row)) * 4096 + m0 + u * 8] =
            *(const bf16x8*)&((char*)Pl)[row * 256 + ((u ^ (row & 7)) << 4)];
    }
}

// ----------------------------------------------------- l reduce (32 slices)
__global__ __launch_bounds__(256) void lred_kernel(
    const float* __restrict__ lpart, float* __restrict__ lsum)
{
    int rr = blockIdx.x * 256 + threadIdx.x;  // 0..8191
    int bb = rr >> 12, r = rr & 4095;
    float s = 0.f;
#pragma unroll
    for (int sl = 0; sl < 32; ++sl)
        s += lpart[(size_t)(bb * 32 + sl) * 4096 + r];
    lsum[rr] = 1.0f / s;
}

// ------------------------------------------------------------ PV GEMM v2
// 128x128, 512 thr, 3-buffer 2-ahead counted vmcnt(4), grid (32,4,2)=1/CU.
__global__ __launch_bounds__(512) void pv_kernel(
    const unsigned short* __restrict__ P, const unsigned short* __restrict__ vT,
    const float* __restrict__ linv, unsigned short* __restrict__ outb, int b0)
{
    int m0 = blockIdx.x * 128, n0 = blockIdx.y * 128, bb = blockIdx.z;
    int b = b0 + bb;
    int t = threadIdx.x, l = t & 63, w = t >> 6;
    int wm = w >> 2, wn = w & 3;
    int lr = l & 15, lg = l >> 4;

    __shared__ __align__(16) unsigned short lds[49152];  // 96 KB
    unsigned short* As = lds;           // 3 x 8192 (128 x 64)
    unsigned short* Bs = lds + 24576;   // 3 x 8192 (128 x 64)

    const unsigned short* A_ = P + (size_t)(bb * 4096 + m0) * 4096;
    const unsigned short* B_ = vT + ((size_t)b * 512 + n0) * 4096;

    auto stage = [&](int s, int buf) {   // 4 vmem instr per thread
        int k0 = s * 64;
        unsigned short* ad = As + buf * 8192;
        unsigned short* bd = Bs + buf * 8192;
#pragma unroll
        for (int c = 0; c < 2; ++c) {
            int flat = c * 512 + t;
            int row = flat >> 3, u = flat & 7;
            g2l16(A_ + (size_t)row * 4096 + k0 + ((u ^ (row & 7)) << 3),
                  ad + (flat << 3));
        }
#pragma unroll
        for (int c = 0; c < 2; ++c) {
            int flat = c * 512 + t;
            int row = flat >> 3, u = flat & 7;
            g2l16(B_ + (size_t)row * 4096 + k0 + ((u ^ (row & 7)) << 3),
                  bd + (flat << 3));
        }
    };

    f32x4 acc[4][2];
#pragma unroll
    for (int i = 0; i < 4; ++i)
#pragma unroll
        for (int j = 0; j < 2; ++j) acc[i][j] = f32x4{0.f, 0.f, 0.f, 0.f};

    stage(0, 0);
    stage(1, 1);
    asm volatile("s_waitcnt vmcnt(4)" ::: "memory");
    __builtin_amdgcn_s_barrier();
    __builtin_amdgcn_sched_barrier(0);

    for (int s = 0; s < 64; ++s) {
        if (s + 2 < 64) stage(s + 2, (s + 2) % 3);
        const unsigned short* Al = As + (s % 3) * 8192;
        const unsigned short* Bl = Bs + (s % 3) * 8192;
        __builtin_amdgcn_s_setprio(1);
#pragma unroll
        for (int ks = 0; ks < 2; ++ks) {
            bf16x8 af[4], bfr[2];
#pragma unroll
            for (int mi = 0; mi < 4; ++mi) {
                int row = wm * 64 + mi * 16 + lr;
                af[mi] = *(const bf16x8*)&Al[(row * 8 + ((ks * 4 + lg) ^ (row & 7))) << 3];
            }
#pragma unroll
            for (int ni = 0; ni < 2; ++ni) {
                int row = wn * 32 + ni * 16 + lr;
                bfr[ni] = *(const bf16x8*)&Bl[(row * 8 + ((ks * 4 + lg) ^ (row & 7))) << 3];
            }
#pragma unroll
            for (int mi = 0; mi < 4; ++mi)
#pragma unroll
                for (int ni = 0; ni < 2; ++ni)
                    acc[mi][ni] = MFMA16(af[mi], bfr[ni], acc[mi][ni]);
        }
        __builtin_amdgcn_s_setprio(0);
        if (s < 62) asm volatile("s_waitcnt vmcnt(4) lgkmcnt(0)" ::: "memory");
        else        asm volatile("s_waitcnt vmcnt(0) lgkmcnt(0)" ::: "memory");
        __builtin_amdgcn_s_barrier();
        __builtin_amdgcn_sched_barrier(0);
    }

#pragma unroll
    for (int mi = 0; mi < 4; ++mi)
#pragma unroll
        for (int r = 0; r < 4; ++r) {
            int row = m0 + wm * 64 + mi * 16 + lg * 4 + r;
            float inv = linv[bb * 4096 + row];
#pragma unroll
            for (int ni = 0; ni < 2; ++ni) {
                int col = n0 + wn * 32 + ni * 16 + lr;
                outb[(size_t)(b * 4096 + row) * 512 + col] =
                    f2bf(acc[mi][ni][r] * inv);
            }
        }
}

// --------------------------------------------------------------- launcher
extern "C" void kernel_launch(void* const* d_in, const int* in_sizes, int n_in,
                              void* d_out, int out_size, void* d_ws, size_t ws_size,
                              hipStream_t stream)
{
    const float* x     = (const float*)d_in[0];
    const float* gamma = (const float*)d_in[1];
    const float* beta  = (const float*)d_in[2];
    const float* Wq = (const float*)d_in[3];
    const float* bq = (const float*)d_in[4];
    const float* Wk = (const float*)d_in[5];
    const float* bk = (const float*)d_in[6];
    const float* Wv = (const float*)d_in[7];
    const float* bv = (const float*)d_in[8];
    const float* Wp = (const float*)d_in[9];
    const float* bp = (const float*)d_in[10];
    float* out = (float*)d_out;

    unsigned short* xn    = (unsigned short*)d_ws;                 // 16384*512 (reused as attn out)
    unsigned short* wqkvt = xn + (size_t)16384 * 512;              // 1536*512
    unsigned short* wpt   = wqkvt + (size_t)1536 * 512;            // 512*512
    unsigned short* qkv   = wpt + (size_t)512 * 512;               // 16384*1536 (V region unused)
    unsigned short* vT    = qkv + (size_t)16384 * 1536;            // 4*512*4096
    unsigned short* P     = vT + (size_t)4 * 512 * 4096;           // 2*4096*4096 (64MB)
    float* lpart = (float*)(P + (size_t)2 * 4096 * 4096);          // 64*4096 f32
    float* linv  = lpart + (size_t)128 * 4096;                     // 8192 f32
    float2* gstats = (float2*)(linv + 8192);                       // 1024 float2

    prep_kernel<<<dim3(5120), dim3(256), 0, stream>>>(
        x, Wq, Wk, Wv, Wp, gstats, wqkvt, wpt);
    gn_apply<<<dim3(2048), dim3(256), 0, stream>>>(x, gamma, beta, gstats, xn);
    gemm_kernel<0><<<dim3(128, 12), dim3(256), 0, stream>>>(
        xn, wqkvt, bq, bk, bv, nullptr, nullptr, qkv, nullptr, vT);

    for (int b0 = 0; b0 < 4; b0 += 2) {
        qk_kernel<<<dim3(2048), dim3(256), 0, stream>>>(qkv, P, lpart, b0);
        lred_kernel<<<dim3(32), dim3(256), 0, stream>>>(lpart, linv);
        pv_kernel<<<dim3(32, 4, 2), dim3(512), 0, stream>>>(P, vT, linv, xn, b0);
    }

    gemm_kernel<1><<<dim3(128, 4), dim3(256), 0, stream>>>(
        xn, wpt, nullptr, nullptr, nullptr, bp, x, nullptr, out, nullptr);
}

// Round 19
// 239.772 us; speedup vs baseline: 1.2140x; 1.0101x over previous
//
#include <hip/hip_runtime.h>
#include <hip/hip_bf16.h>

typedef __attribute__((ext_vector_type(8))) short bf16x8;
typedef __attribute__((ext_vector_type(4))) float f32x4;
typedef __attribute__((ext_vector_type(4))) unsigned short u16x4;

#define MFMA16(a, b, c) __builtin_amdgcn_mfma_f32_16x16x32_bf16(a, b, c, 0, 0, 0)

#define SCALE 0.21022410381342865f /* 512^(-1/4) */

__device__ __forceinline__ unsigned short f2bf(float f) {
    union { float f; unsigned u; } v; v.f = f;
    unsigned r = v.u + 0x7FFF + ((v.u >> 16) & 1);
    return (unsigned short)(r >> 16);
}

__device__ __forceinline__ unsigned cvtpk(float lo, float hi) {
    unsigned r;
    asm("v_cvt_pk_bf16_f32 %0, %1, %2" : "=v"(r) : "v"(lo), "v"(hi));
    return r;
}

typedef __attribute__((address_space(3))) void lds_void;
typedef const __attribute__((address_space(1))) void gbl_void;
__device__ __forceinline__ void g2l16(const void* g, void* l) {
    __builtin_amdgcn_global_load_lds((gbl_void*)g, (lds_void*)l, 16, 0, 0);
}

#define PHASE_BARRIER() do { \
    asm volatile("s_waitcnt vmcnt(0) lgkmcnt(0)" ::: "memory"); \
    __builtin_amdgcn_s_barrier(); \
    __builtin_amdgcn_sched_barrier(0); \
} while (0)

#define LGKM_BARRIER() do { \
    asm volatile("s_waitcnt lgkmcnt(0)" ::: "memory"); \
    __builtin_amdgcn_s_barrier(); \
    __builtin_amdgcn_sched_barrier(0); \
} while (0)

// --------------------------------------- prep: gn_stats + weight cast/T
// grid 5120: blocks 0..4095 = wprep work, 4096..5119 = gn stats partials.
__global__ __launch_bounds__(256) void prep_kernel(
    const float* __restrict__ x,
    const float* __restrict__ Wq, const float* __restrict__ Wk,
    const float* __restrict__ Wv, const float* __restrict__ Wp,
    float2* __restrict__ gstats,
    unsigned short* __restrict__ wqkvt, unsigned short* __restrict__ wpt)
{
    __shared__ float rs_[4], rss_[4];
    if (blockIdx.x < 4096) {
        int idx = blockIdx.x * 256 + threadIdx.x; // 1,048,576 total
        if (idx < 786432) {
            int n = idx >> 9, k = idx & 511;
            int j = n >> 9, nn = n & 511;
            const float* W = (j == 0) ? Wq : (j == 1) ? Wk : Wv;
            wqkvt[idx] = f2bf(W[k * 512 + nn]);
        } else {
            int i2 = idx - 786432;
            int n = i2 >> 9, k = i2 & 511;
            wpt[i2] = f2bf(Wp[k * 512 + n]);
        }
        return;
    }
    int id = blockIdx.x - 4096;
    int b = id >> 8, rem = id & 255;
    int g = rem >> 3, sl = rem & 7;
    int t = threadIdx.x;
    const float4* xf4 = (const float4*)x;
    size_t base4 = (size_t)b * (4096 * 128) + g * 4;

    float s = 0.f, ss = 0.f;
#pragma unroll
    for (int i = 0; i < 8; ++i) {
        int flat = i * 256 + t;
        int hw = sl * 512 + (flat >> 2), c4 = flat & 3;
        float4 v = xf4[base4 + (size_t)hw * 128 + c4];
        s  += v.x + v.y + v.z + v.w;
        ss += v.x * v.x + v.y * v.y + v.z * v.z + v.w * v.w;
    }
    for (int m = 32; m >= 1; m >>= 1) { s += __shfl_xor(s, m); ss += __shfl_xor(ss, m); }
    int wv = t >> 6;
    if ((t & 63) == 0) { rs_[wv] = s; rss_[wv] = ss; }
    __syncthreads();
    if (t == 0) {
        float2 o;
        o.x = rs_[0] + rs_[1] + rs_[2] + rs_[3];
        o.y = rss_[0] + rss_[1] + rss_[2] + rss_[3];
        gstats[id] = o;
    }
}

// ------------------------------------------------------- GroupNorm apply
__global__ __launch_bounds__(256) void gn_apply(
    const float* __restrict__ x, const float* __restrict__ gamma,
    const float* __restrict__ beta, const float2* __restrict__ gstats,
    unsigned short* __restrict__ xn)
{
    int id = blockIdx.x;
    int b = id >> 9, rem = id & 511;
    int g = rem >> 4, sl = rem & 15;
    int t = threadIdx.x;

    float s = 0.f, ss = 0.f;
#pragma unroll
    for (int i = 0; i < 8; ++i) {
        float2 p = gstats[(b * 32 + g) * 8 + i];
        s += p.x; ss += p.y;
    }
    float mean = s * (1.f / 65536.f);
    float var  = ss * (1.f / 65536.f) - mean * mean;
    float rstd = rsqrtf(var + 1e-6f);

    const float4* xf4 = (const float4*)x;
    const float4* g4 = (const float4*)gamma;
    const float4* b4 = (const float4*)beta;
    size_t base4 = (size_t)b * (4096 * 128) + g * 4;
#pragma unroll
    for (int i = 0; i < 4; ++i) {
        int flat = i * 256 + t;
        int hw = sl * 256 + (flat >> 2), c4 = flat & 3;
        float4 v  = xf4[base4 + (size_t)hw * 128 + c4];
        float4 gm = g4[g * 4 + c4], bt = b4[g * 4 + c4];
        u16x4 o;
        o.x = f2bf((v.x - mean) * rstd * gm.x + bt.x);
        o.y = f2bf((v.y - mean) * rstd * gm.y + bt.y);
        o.z = f2bf((v.z - mean) * rstd * gm.z + bt.z);
        o.w = f2bf((v.w - mean) * rstd * gm.w + bt.w);
        *(u16x4*)&xn[(size_t)(b * 4096 + hw) * 512 + g * 16 + c4 * 4] = o;
    }
}

// ------------------------------------------------------------- bf16 GEMM v3
// MODE 0 with blockIdx.y >= 8 = V tile: bias-add + transpose-repack via a
// 32 KB unit-swizzled LDS overlay, stored coalesced directly to vT.
template <int MODE>
__global__ __launch_bounds__(256, 4) void gemm_kernel(
    const unsigned short* __restrict__ A, const unsigned short* __restrict__ Bt,
    const float* __restrict__ bias_q, const float* __restrict__ bias_k,
    const float* __restrict__ bias_v, const float* __restrict__ bias_p,
    const float* __restrict__ resid,
    unsigned short* __restrict__ Cbf, float* __restrict__ Cf,
    unsigned short* __restrict__ vTo)
{
    int m0 = blockIdx.x * 128;
    int n0 = blockIdx.y * 128;
    int t = threadIdx.x;
    int l = t & 63, w = t >> 6;
    int wm = w >> 1, wn = w & 1;
    int lr = l & 15, lg = l >> 4;

    __shared__ __align__(16) unsigned short lds[16384];  // 32 KB
    unsigned short* As = lds;
    unsigned short* Bs = lds + 8192;

    const unsigned short* A_ = A + (size_t)m0 * 512;
    const unsigned short* B_ = Bt + (size_t)n0 * 512;

    auto stage = [&](int s) {
        int k0 = s * 64;
#pragma unroll
        for (int c = 0; c < 4; ++c) {
            int flat = c * 256 + t;
            int row = flat >> 3, u = flat & 7;
            g2l16(A_ + (size_t)row * 512 + k0 + ((u ^ (row & 7)) << 3),
                  As + (flat << 3));
        }
#pragma unroll
        for (int c = 0; c < 4; ++c) {
            int flat = c * 256 + t;
            int row = flat >> 3, u = flat & 7;
            g2l16(B_ + (size_t)row * 512 + k0 + ((u ^ (row & 7)) << 3),
                  Bs + (flat << 3));
        }
    };

    f32x4 acc[4][4];
#pragma unroll
    for (int i = 0; i < 4; ++i)
#pragma unroll
        for (int j = 0; j < 4; ++j) acc[i][j] = f32x4{0.f, 0.f, 0.f, 0.f};

    for (int s = 0; s < 8; ++s) {
        if (s) LGKM_BARRIER();
        stage(s);
        PHASE_BARRIER();
        __builtin_amdgcn_s_setprio(1);
#pragma unroll
        for (int ks = 0; ks < 2; ++ks) {
            bf16x8 af[4], bfr[4];
#pragma unroll
            for (int mi = 0; mi < 4; ++mi) {
                int row = wm * 64 + mi * 16 + lr;
                af[mi] = *(const bf16x8*)&As[(row * 8 + ((ks * 4 + lg) ^ (row & 7))) << 3];
            }
#pragma unroll
            for (int ni = 0; ni < 4; ++ni) {
                int row = wn * 64 + ni * 16 + lr;
                bfr[ni] = *(const bf16x8*)&Bs[(row * 8 + ((ks * 4 + lg) ^ (row & 7))) << 3];
            }
#pragma unroll
            for (int mi = 0; mi < 4; ++mi)
#pragma unroll
                for (int ni = 0; ni < 4; ++ni)
                    acc[mi][ni] = MFMA16(af[mi], bfr[ni], acc[mi][ni]);
        }
        __builtin_amdgcn_s_setprio(0);
    }

    if (MODE == 0 && blockIdx.y >= 8) {
        // ---- V tile: bias + transpose-repack via LDS, store to vT
        LGKM_BARRIER();
        unsigned short* Tl = lds;   // 128 d x 128 tok (unit-swizzled), 32 KB
#pragma unroll
        for (int ni = 0; ni < 4; ++ni) {
            int d_loc = wn * 64 + ni * 16 + lr;
            float bias = bias_v[n0 - 1024 + d_loc];
#pragma unroll
            for (int mi = 0; mi < 4; ++mi) {
                int tok = wm * 64 + mi * 16 + lg * 4;
                int u = tok >> 3, off = tok & 7;
                unsigned* dst = (unsigned*)&((char*)Tl)[
                    d_loc * 256 + ((u ^ (d_loc & 7)) << 4) + off * 2];
                dst[0] = cvtpk(acc[mi][ni][0] + bias, acc[mi][ni][1] + bias);
                dst[1] = cvtpk(acc[mi][ni][2] + bias, acc[mi][ni][3] + bias);
            }
        }
        LGKM_BARRIER();
        int b = m0 >> 12, nl0 = m0 & 4095;
        int d0 = n0 - 1024;
#pragma unroll
        for (int c = 0; c < 8; ++c) {
            int flat = c * 256 + t;
            int row = flat >> 4, u = flat & 15;
            *(bf16x8*)&vTo[((size_t)(b * 512 + d0 + row)) * 4096 + nl0 + u * 8] =
                *(const bf16x8*)&((char*)Tl)[row * 256 + ((u ^ (row & 7)) << 4)];
        }
        return;
    }

#pragma unroll
    for (int mi = 0; mi < 4; ++mi)
#pragma unroll
        for (int ni = 0; ni < 4; ++ni)
#pragma unroll
            for (int r = 0; r < 4; ++r) {
                int row = m0 + wm * 64 + mi * 16 + lg * 4 + r;
                int col = n0 + wn * 64 + ni * 16 + lr;
                float val = acc[mi][ni][r];
                if (MODE == 0) {
                    float bias = (col < 512) ? bias_q[col] : bias_k[col - 512];
                    Cbf[(size_t)row * 1536 + col] = f2bf((val + bias) * SCALE);
                } else {
                    Cf[(size_t)row * 512 + col] =
                        val + bias_p[col] + resid[(size_t)row * 512 + col];
                }
            }
}

// ------------------------------------------------------------ QK^T + exp v5
// grid (1024, nbat): blockIdx.y = chunk-relative batch. Per y-slice all 8
// XCDs work one batch: nb = xcd*4 + (i&3), mb = i>>2 (bijective; 4 q-panels
// + full K per XCD = ~4.5 MB working set).
__global__ __launch_bounds__(256, 4) void qk_kernel(
    const unsigned short* __restrict__ qkv, unsigned short* __restrict__ P,
    float* __restrict__ lpart, int b0)
{
    int W = blockIdx.x;
    int bb = blockIdx.y;
    int xcd = W & 7, i = W >> 3;        // i 0..127
    int nb = xcd * 4 + (i & 3);         // q-block 0..31
    int mb = i >> 2;                    // kv-block 0..31
    int m0 = mb * 128, n0 = nb * 128;
    int b = b0 + bb;

    int t = threadIdx.x, l = t & 63, w = t >> 6;
    int wm = w >> 1, wn = w & 1;
    int lr = l & 15, lg = l >> 4;

    __shared__ __align__(16) unsigned short lds[16896];  // 33 KB
    unsigned short* As = lds;             // K tile 128x64 (kv rows)
    unsigned short* Bs = lds + 8192;      // Q tile 128x64 (q rows)
    float* Lw = (float*)(lds + 16384);    // 2 x 128 row-sum halves

    const unsigned short* A_ = qkv + (size_t)(b * 4096 + m0) * 1536 + 512;  // K
    const unsigned short* B_ = qkv + (size_t)(b * 4096 + n0) * 1536;        // Q

    auto stage = [&](int s) {
        int k0 = s * 64;
#pragma unroll
        for (int c = 0; c < 4; ++c) {
            int flat = c * 256 + t;
            int row = flat >> 3, u = flat & 7;
            g2l16(A_ + (size_t)row * 1536 + k0 + ((u ^ (row & 7)) << 3),
                  As + (flat << 3));
        }
#pragma unroll
        for (int c = 0; c < 4; ++c) {
            int flat = c * 256 + t;
            int row = flat >> 3, u = flat & 7;
            g2l16(B_ + (size_t)row * 1536 + k0 + ((u ^ (row & 7)) << 3),
                  Bs + (flat << 3));
        }
    };

    f32x4 acc[4][4];
#pragma unroll
    for (int mi = 0; mi < 4; ++mi)
#pragma unroll
        for (int ni = 0; ni < 4; ++ni) acc[mi][ni] = f32x4{0.f, 0.f, 0.f, 0.f};

    for (int s = 0; s < 8; ++s) {
        if (s) LGKM_BARRIER();
        stage(s);
        PHASE_BARRIER();
        __builtin_amdgcn_s_setprio(1);
#pragma unroll
        for (int ks = 0; ks < 2; ++ks) {
            bf16x8 af[4], bfr[4];
#pragma unroll
            for (int mi = 0; mi < 4; ++mi) {
                int row = wm * 64 + mi * 16 + lr;
                af[mi] = *(const bf16x8*)&As[(row * 8 + ((ks * 4 + lg) ^ (row & 7))) << 3];
            }
#pragma unroll
            for (int ni = 0; ni < 4; ++ni) {
                int row = wn * 64 + ni * 16 + lr;
                bfr[ni] = *(const bf16x8*)&Bs[(row * 8 + ((ks * 4 + lg) ^ (row & 7))) << 3];
            }
#pragma unroll
            for (int mi = 0; mi < 4; ++mi)
#pragma unroll
                for (int ni = 0; ni < 4; ++ni)
                    acc[mi][ni] = MFMA16(af[mi], bfr[ni], acc[mi][ni]);
        }
        __builtin_amdgcn_s_setprio(0);
    }
    LGKM_BARRIER();

    // ---- epilogue: exp + in-lane row sums + packed P writes (S^T layout)
    unsigned short* Pl = lds;             // 128 q x 128 kv = 32 KB overlay
    {
        float sums[4] = {0.f, 0.f, 0.f, 0.f};
#pragma unroll
        for (int mi = 0; mi < 4; ++mi) {
            int u = wm * 8 + mi * 2 + (lg >> 1);
            int half = lg & 1;
#pragma unroll
            for (int ni = 0; ni < 4; ++ni) {
                float p0 = __expf(acc[mi][ni][0]);
                float p1 = __expf(acc[mi][ni][1]);
                float p2 = __expf(acc[mi][ni][2]);
                float p3 = __expf(acc[mi][ni][3]);
                sums[ni] += p0 + p1 + p2 + p3;
                int q = wn * 64 + ni * 16 + lr;
                unsigned* dst = (unsigned*)&((char*)Pl)[
                    q * 256 + ((u ^ (q & 7)) << 4) + (half << 3)];
                dst[0] = cvtpk(p0, p1);
                dst[1] = cvtpk(p2, p3);
            }
        }
#pragma unroll
        for (int ni = 0; ni < 4; ++ni) {
            float v = sums[ni];
            v += __shfl_xor(v, 16);
            v += __shfl_xor(v, 32);
            if (lg == 0) Lw[wm * 128 + wn * 64 + ni * 16 + lr] = v;
        }
    }
    LGKM_BARRIER();

    if (t < 128)
        lpart[(size_t)(bb * 32 + mb) * 4096 + n0 + t] = Lw[t] + Lw[128 + t];

    // coalesced P store: P[q_global][kv_global], 256 B per q-row
#pragma unroll
    for (int c = 0; c < 8; ++c) {
        int flat = c * 256 + t;
        int row = flat >> 4, u = flat & 15;
        *(bf16x8*)&P[((size_t)(bb * 4096 + n0 + row)) * 4096 + m0 + u * 8] =
            *(const bf16x8*)&((char*)Pl)[row * 256 + ((u ^ (row & 7)) << 4)];
    }
}

// ----------------------------------------------------- l reduce (32 slices)
__global__ __launch_bounds__(256) void lred_kernel(
    const float* __restrict__ lpart, float* __restrict__ lsum)
{
    int rr = blockIdx.x * 256 + threadIdx.x;
    int bb = rr >> 12, r = rr & 4095;
    float s = 0.f;
#pragma unroll
    for (int sl = 0; sl < 32; ++sl)
        s += lpart[(size_t)(bb * 32 + sl) * 4096 + r];
    lsum[rr] = 1.0f / s;
}

// ------------------------------------------------------------ PV GEMM v2
// 128x128, 512 thr, 3-buffer 2-ahead counted vmcnt(4), 1 block/CU.
__global__ __launch_bounds__(512) void pv_kernel(
    const unsigned short* __restrict__ P, const unsigned short* __restrict__ vT,
    const float* __restrict__ linv, unsigned short* __restrict__ outb, int b0)
{
    int m0 = blockIdx.x * 128, n0 = blockIdx.y * 128, bb = blockIdx.z;
    int b = b0 + bb;
    int t = threadIdx.x, l = t & 63, w = t >> 6;
    int wm = w >> 2, wn = w & 3;
    int lr = l & 15, lg = l >> 4;

    __shared__ __align__(16) unsigned short lds[49152];  // 96 KB
    unsigned short* As = lds;           // 3 x 8192 (128 x 64)
    unsigned short* Bs = lds + 24576;   // 3 x 8192 (128 x 64)

    const unsigned short* A_ = P + (size_t)(bb * 4096 + m0) * 4096;
    const unsigned short* B_ = vT + ((size_t)b * 512 + n0) * 4096;

    auto stage = [&](int s, int buf) {
        int k0 = s * 64;
        unsigned short* ad = As + buf * 8192;
        unsigned short* bd = Bs + buf * 8192;
#pragma unroll
        for (int c = 0; c < 2; ++c) {
            int flat = c * 512 + t;
            int row = flat >> 3, u = flat & 7;
            g2l16(A_ + (size_t)row * 4096 + k0 + ((u ^ (row & 7)) << 3),
                  ad + (flat << 3));
        }
#pragma unroll
        for (int c = 0; c < 2; ++c) {
            int flat = c * 512 + t;
            int row = flat >> 3, u = flat & 7;
            g2l16(B_ + (size_t)row * 4096 + k0 + ((u ^ (row & 7)) << 3),
                  bd + (flat << 3));
        }
    };

    f32x4 acc[4][2];
#pragma unroll
    for (int i = 0; i < 4; ++i)
#pragma unroll
        for (int j = 0; j < 2; ++j) acc[i][j] = f32x4{0.f, 0.f, 0.f, 0.f};

    stage(0, 0);
    stage(1, 1);
    asm volatile("s_waitcnt vmcnt(4)" ::: "memory");
    __builtin_amdgcn_s_barrier();
    __builtin_amdgcn_sched_barrier(0);

    for (int s = 0; s < 64; ++s) {
        if (s + 2 < 64) stage(s + 2, (s + 2) % 3);
        const unsigned short* Al = As + (s % 3) * 8192;
        const unsigned short* Bl = Bs + (s % 3) * 8192;
        __builtin_amdgcn_s_setprio(1);
#pragma unroll
        for (int ks = 0; ks < 2; ++ks) {
            bf16x8 af[4], bfr[2];
#pragma unroll
            for (int mi = 0; mi < 4; ++mi) {
                int row = wm * 64 + mi * 16 + lr;
                af[mi] = *(const bf16x8*)&Al[(row * 8 + ((ks * 4 + lg) ^ (row & 7))) << 3];
            }
#pragma unroll
            for (int ni = 0; ni < 2; ++ni) {
                int row = wn * 32 + ni * 16 + lr;
                bfr[ni] = *(const bf16x8*)&Bl[(row * 8 + ((ks * 4 + lg) ^ (row & 7))) << 3];
            }
#pragma unroll
            for (int mi = 0; mi < 4; ++mi)
#pragma unroll
                for (int ni = 0; ni < 2; ++ni)
                    acc[mi][ni] = MFMA16(af[mi], bfr[ni], acc[mi][ni]);
        }
        __builtin_amdgcn_s_setprio(0);
        if (s < 62) asm volatile("s_waitcnt vmcnt(4) lgkmcnt(0)" ::: "memory");
        else        asm volatile("s_waitcnt vmcnt(0) lgkmcnt(0)" ::: "memory");
        __builtin_amdgcn_s_barrier();
        __builtin_amdgcn_sched_barrier(0);
    }

#pragma unroll
    for (int mi = 0; mi < 4; ++mi)
#pragma unroll
        for (int r = 0; r < 4; ++r) {
            int row = m0 + wm * 64 + mi * 16 + lg * 4 + r;
            float inv = linv[bb * 4096 + row];
#pragma unroll
            for (int ni = 0; ni < 2; ++ni) {
                int col = n0 + wn * 32 + ni * 16 + lr;
                outb[(size_t)(b * 4096 + row) * 512 + col] =
                    f2bf(acc[mi][ni][r] * inv);
            }
        }
}

// --------------------------------------------------------------- launcher
extern "C" void kernel_launch(void* const* d_in, const int* in_sizes, int n_in,
                              void* d_out, int out_size, void* d_ws, size_t ws_size,
                              hipStream_t stream)
{
    const float* x     = (const float*)d_in[0];
    const float* gamma = (const float*)d_in[1];
    const float* beta  = (const float*)d_in[2];
    const float* Wq = (const float*)d_in[3];
    const float* bq = (const float*)d_in[4];
    const float* Wk = (const float*)d_in[5];
    const float* bk = (const float*)d_in[6];
    const float* Wv = (const float*)d_in[7];
    const float* bv = (const float*)d_in[8];
    const float* Wp = (const float*)d_in[9];
    const float* bp = (const float*)d_in[10];
    float* out = (float*)d_out;

    // workspace layout (head fixed; P sized by chunk count, tail after P)
    unsigned short* xn    = (unsigned short*)d_ws;                 // 16384*512
    unsigned short* wqkvt = xn + (size_t)16384 * 512;              // 1536*512
    unsigned short* wpt   = wqkvt + (size_t)1536 * 512;            // 512*512
    unsigned short* qkv   = wpt + (size_t)512 * 512;               // 16384*1536 (V region unused)
    unsigned short* vT    = qkv + (size_t)16384 * 1536;            // 4*512*4096
    unsigned short* P     = vT + (size_t)4 * 512 * 4096;

    size_t head_elems = (size_t)16384 * 512 + 1536 * 512 + 512 * 512 +
                        (size_t)16384 * 1536 + (size_t)4 * 512 * 4096;
    size_t tail_bytes = ((size_t)128 * 4096 + 16384 + 2048 * 2) * sizeof(float);
    size_t need4 = head_elems * 2 + (size_t)4 * 4096 * 4096 * 2 + tail_bytes;
    int nchunk = (ws_size >= need4) ? 4 : 2;

    float* lpart = (float*)(P + (size_t)nchunk * 4096 * 4096);     // 128*4096 f32
    float* linv  = lpart + (size_t)128 * 4096;                     // 16384 f32
    float2* gstats = (float2*)(linv + 16384);                      // 1024 float2

    prep_kernel<<<dim3(5120), dim3(256), 0, stream>>>(
        x, Wq, Wk, Wv, Wp, gstats, wqkvt, wpt);
    gn_apply<<<dim3(2048), dim3(256), 0, stream>>>(x, gamma, beta, gstats, xn);
    gemm_kernel<0><<<dim3(128, 12), dim3(256), 0, stream>>>(
        xn, wqkvt, bq, bk, bv, nullptr, nullptr, qkv, nullptr, vT);

    for (int b0 = 0; b0 < 4; b0 += nchunk) {
        qk_kernel<<<dim3(1024, nchunk), dim3(256), 0, stream>>>(qkv, P, lpart, b0);
        lred_kernel<<<dim3(16 * nchunk), dim3(256), 0, stream>>>(lpart, linv);
        pv_kernel<<<dim3(32, 4, nchunk), dim3(512), 0, stream>>>(P, vT, linv, xn, b0);
    }

    gemm_kernel<1><<<dim3(128, 4), dim3(256), 0, stream>>>(
        xn, wpt, nullptr, nullptr, nullptr, bp, x, nullptr, out, nullptr);
}